// Round 8
// baseline (13861.819 us; speedup 1.0000x reference)
//
#include <hip/hip_runtime.h>
#include <cstdint>
#include <cstddef>

#define TCHUNK 128
#define NCHUNK 8
#define BATCH 32
#define IDIM 128
#define HDIM 512
#define GDIM 2048
#define ODIM 10
#define NBLK 256
#define XPSTEP (GDIM * BATCH)
#define SLAB_F 16384            // floats per t-slab: 8 groups x 4 chains x 512
#define SLAB_B (SLAB_F * 4)

typedef float f4 __attribute__((ext_vector_type(4)));
typedef float f2 __attribute__((ext_vector_type(2)));

// LLC-visible store (sc0 sc1): one-way, fire-and-forget, placement-independent
__device__ __forceinline__ void llc_store(float* p, float v) {
  asm volatile("global_store_dword %0, %1, off sc0 sc1" :: "v"(p), "v"(v) : "memory");
}
// quad (4-lane) butterfly sum via DPP quad_perm — pure VALU
__device__ __forceinline__ float quad_sum(float x) {
  int t = __builtin_amdgcn_update_dpp(0, __float_as_int(x), 0xB1, 0xF, 0xF, true);
  x += __int_as_float(t);
  t = __builtin_amdgcn_update_dpp(0, __float_as_int(x), 0x4E, 0xF, 0xF, true);
  x += __int_as_float(t);
  return x;
}
// 16-lane butterfly over the qt groups (lanes l, l^4-ish via row rotates)
__device__ __forceinline__ float ror16_sum(float x) {
  int t = __builtin_amdgcn_update_dpp(0, __float_as_int(x), 0x124, 0xF, 0xF, true); // row_ror:4
  x += __int_as_float(t);
  t = __builtin_amdgcn_update_dpp(0, __float_as_int(x), 0x128, 0xF, 0xF, true);     // row_ror:8
  x += __int_as_float(t);
  return x;
}
__device__ __forceinline__ float fast_sig(float x) {
  return 1.f / (1.f + __expf(-x));
}
__device__ __forceinline__ float fast_tanh(float x) {
  return 2.f / (1.f + __expf(-2.f * x)) - 1.f;
}

#define BARRIER() do {                                                      \
    asm volatile("s_waitcnt lgkmcnt(0)" ::: "memory");                      \
    __builtin_amdgcn_sched_barrier(0);                                      \
    __builtin_amdgcn_s_barrier();                                           \
    __builtin_amdgcn_sched_barrier(0);                                      \
  } while (0)

// ---------------------------------------------------------------------------
// proj: P[tt][n][b] = sum_k X[tt*32+b][k] * W[n][k] + bias[n]
// ---------------------------------------------------------------------------
template<int K>
__launch_bounds__(256, 2)
__global__ void proj_kernel(const float* __restrict__ X,
                            const float* __restrict__ W,
                            const float* __restrict__ bias,
                            float* __restrict__ P) {
  __shared__ float Xs[8][132];
  __shared__ float Ws[8][132];
  const int tid = threadIdx.x;
  const int n0 = blockIdx.x * 128;
  const int m0 = blockIdx.y * 128;
  const int tx = tid & 15, ty = tid >> 4;
  const int lm = tid >> 1;
  const int kq = (tid & 1) * 4;
  f2 acc2[8][4];
#pragma unroll
  for (int i = 0; i < 8; ++i)
#pragma unroll
    for (int j = 0; j < 4; ++j) acc2[i][j] = (f2){0.f, 0.f};

  for (int k0 = 0; k0 < K; k0 += 8) {
    const float4 xv = *(const float4*)&X[(size_t)(m0 + lm) * K + k0 + kq];
    const float4 wv = *(const float4*)&W[(size_t)(n0 + lm) * K + k0 + kq];
    __syncthreads();
    Xs[kq + 0][lm] = xv.x; Xs[kq + 1][lm] = xv.y; Xs[kq + 2][lm] = xv.z; Xs[kq + 3][lm] = xv.w;
    Ws[kq + 0][lm] = wv.x; Ws[kq + 1][lm] = wv.y; Ws[kq + 2][lm] = wv.z; Ws[kq + 3][lm] = wv.w;
    __syncthreads();
#pragma unroll
    for (int kk = 0; kk < 8; ++kk) {
      float a[8];
      *(float4*)&a[0] = *(const float4*)&Xs[kk][ty * 8];
      *(float4*)&a[4] = *(const float4*)&Xs[kk][ty * 8 + 4];
      f2 b2[4];
#pragma unroll
      for (int jp = 0; jp < 4; ++jp) b2[jp] = *(const f2*)&Ws[kk][tx * 8 + 2 * jp];
#pragma unroll
      for (int i = 0; i < 8; ++i)
#pragma unroll
        for (int jp = 0; jp < 4; ++jp) acc2[i][jp] += b2[jp] * a[i];
    }
  }
  const int mb = m0 + ty * 8;
  const int t  = mb >> 5;
  const int b0 = mb & 31;
#pragma unroll
  for (int j = 0; j < 8; ++j) {
    const int n = n0 + tx * 8 + j;
    const float bj = bias[n];
    float* dst = &P[((size_t)t * GDIM + n) * BATCH + b0];
#pragma unroll
    for (int i = 0; i < 8; ++i)
      dst[i] = ((j & 1) ? acc2[i][j >> 1].y : acc2[i][j >> 1].x) + bj;
  }
}

// ---------------------------------------------------------------------------
// scan: sentinel-exchange, gate-complete-in-wave LSTM recurrence.
// 256 blocks, 1/CU (81KB LDS). Group g=bid&7 owns batches 4g..4g+3;
// rank=bid>>3 owns h-slots rank*16..+15. Lane (rg,qt,sub) of wave w:
//   - holds the 4 gate rows of slot = rank*16+4w+rg over k-slice sgn=4qt+sub
//   - computes partials for all 4 chains (f2 pk_fma), quad-reduce over sub,
//     selects chain=sub, ror16-reduce over qt -> full pre-acts in-lane
//   - applies activations, updates (slot, chain sub)'s c/h, fires sc0sc1 store
// One barrier/step (stage-ready), double-buffered h LDS, XOR bank swizzle.
// Exchange: write-once slabs hb[t][g][chain][512], sentinel 0xFFFFFFFF.
// ---------------------------------------------------------------------------
__launch_bounds__(256, 1)
__global__ void scan_kernel(const float* __restrict__ xp,    // [TCHUNK][GDIM][BATCH]
                            const float* __restrict__ Whh,   // [GDIM][HDIM]
                            float* __restrict__ hout,        // [TCHUNK][BATCH][HDIM]
                            float* __restrict__ hb,          // [TCHUNK+1][8][4][512]
                            float* __restrict__ ccur,        // [BATCH][HDIM]
                            int first) {
  __shared__ float h_s[2][2048];    // double-buffered, XOR-swizzled [slice][k][c]
  __shared__ float pad[16640];      // 65KB -> 81KB total -> 1 block/CU

  const int tid = threadIdx.x, bid = blockIdx.x;
  const int g = bid & 7, rank = bid >> 3, slot16 = rank * 16;
  const int w = tid >> 6, l = tid & 63;
  const int rg = l >> 4, qt = (l >> 2) & 3, sub = l & 3;
  const int sgn = 4 * qt + sub;          // this lane's 32-wide k-slice
  const int kb = 32 * sgn;
  const int slot = slot16 + 4 * w + rg;  // this lane's h-slot
  const int bxk = (16 * sub) ^ (64 * (qt & 1));   // byte-level XOR swizzle key

  // ---- W: 4 gate rows of `slot`, k in [kb,kb+32), into VGPRs ----
  float wreg[4][32];
#pragma unroll
  for (int q = 0; q < 4; ++q) {
    const float* wp = Whh + (size_t)(q * HDIM + slot) * HDIM + kb;
#pragma unroll
    for (int q8 = 0; q8 < 8; ++q8) {
      const f4 v = *(const f4*)&wp[q8 * 4];
      wreg[q][q8 * 4 + 0] = v.x; wreg[q][q8 * 4 + 1] = v.y;
      wreg[q][q8 * 4 + 2] = v.z; wreg[q][q8 * 4 + 3] = v.w;
    }
  }

  // ---- staging role (t-invariant): chain cl, 8 words K = 128w+8m+i ----
  const int cl = l >> 4, m = l & 15;
  const int sgS = 4 * w + (m >> 2);
  const int bxkS = (16 * (sgS & 3)) ^ (64 * ((sgS >> 2) & 1));
  int dsb[8];                            // byte offsets within one h_s buffer
#pragma unroll
  for (int i = 0; i < 8; ++i) {
    const int kk = 8 * (m & 3) + i;
    dsb[i] = (512 * sgS) ^ (16 * kk) ^ bxkS | (4 * cl);
  }
  const int srcoff = cl * 512 + 128 * w + 8 * m;

  // xp base for this lane's (slot, chain sub); gate q adds q*HDIM*BATCH
  const float* xq = xp + (size_t)slot * BATCH + g * 4 + sub;

  float c_st = 0.f;
  if (!first) c_st = ccur[(size_t)(g * 4 + sub) * HDIM + slot];

  // ---- prologue: stage h(0) (slab 0 holds real data) into buffer 0 ----
  {
    const float* src = hb + g * 2048 + srcoff;
    f4 va, vb;
    int guard = 0;
    while (true) {
      asm volatile("global_load_dwordx4 %0, %2, off sc0 sc1\n\t"
                   "global_load_dwordx4 %1, %3, off sc0 sc1\n\t"
                   "s_waitcnt vmcnt(0)"
                   : "=&v"(va), "=&v"(vb) : "v"(src), "v"(src + 4) : "memory");
      const bool ok =
          __float_as_uint(va.x) != 0xFFFFFFFFu && __float_as_uint(va.y) != 0xFFFFFFFFu &&
          __float_as_uint(va.z) != 0xFFFFFFFFu && __float_as_uint(va.w) != 0xFFFFFFFFu &&
          __float_as_uint(vb.x) != 0xFFFFFFFFu && __float_as_uint(vb.y) != 0xFFFFFFFFu &&
          __float_as_uint(vb.z) != 0xFFFFFFFFu && __float_as_uint(vb.w) != 0xFFFFFFFFu;
      if (__all(ok) || ++guard > 100000) break;
      __builtin_amdgcn_s_sleep(1);
    }
    char* hs0 = (char*)&h_s[0][0];
    *(float*)(hs0 + dsb[0]) = va.x; *(float*)(hs0 + dsb[1]) = va.y;
    *(float*)(hs0 + dsb[2]) = va.z; *(float*)(hs0 + dsb[3]) = va.w;
    *(float*)(hs0 + dsb[4]) = vb.x; *(float*)(hs0 + dsb[5]) = vb.y;
    *(float*)(hs0 + dsb[6]) = vb.z; *(float*)(hs0 + dsb[7]) = vb.w;
  }
  BARRIER();

#pragma unroll 1
  for (int tt = 0; tt < TCHUNK; ++tt) {
    // xp for this lane's 4 gates (issued early; used ~300cyc later)
    float xq4[4];
#pragma unroll
    for (int q = 0; q < 4; ++q)
      xq4[q] = xq[(size_t)tt * XPSTEP + (size_t)q * (HDIM * BATCH)];

    // ---- dot: 4 gate rows x 4 chains over this lane's 32-k slice ----
    const unsigned sbase = (unsigned)(8192 * (tt & 1) + 512 * sgn) ^ (unsigned)bxk;
    const char* hsb = (const char*)&h_s[0][0];
    f2 a01[4], a23[4];
#pragma unroll
    for (int q = 0; q < 4; ++q) { a01[q] = (f2){0.f, 0.f}; a23[q] = (f2){0.f, 0.f}; }
#pragma unroll
    for (int kk = 0; kk < 32; ++kk) {
      const f4 hv = *(const f4*)(hsb + (sbase ^ (unsigned)(16 * kk)));
      const f2 h01 = {hv.x, hv.y}, h23 = {hv.z, hv.w};
#pragma unroll
      for (int q = 0; q < 4; ++q) {
        a01[q] += h01 * wreg[q][kk];
        a23[q] += h23 * wreg[q][kk];
      }
    }
    // ---- reduce: quad over sub -> select chain=sub -> ror16 over qt ----
    float pre[4];
#pragma unroll
    for (int q = 0; q < 4; ++q) {
      const f2 p01 = { quad_sum(a01[q].x), quad_sum(a01[q].y) };
      const f2 p23 = { quad_sum(a23[q].x), quad_sum(a23[q].y) };
      const f2 ab = (sub & 2) ? p23 : p01;
      const float sel = (sub & 1) ? ab.y : ab.x;
      pre[q] = ror16_sum(sel) + xq4[q];
    }
    // ---- activations + c/h update (in-lane; qt groups redundant x4) ----
    const float ig = fast_sig(pre[0]);
    const float fg = fast_sig(pre[1]);
    const float gg = fast_tanh(pre[2]);
    const float og = fast_sig(pre[3]);
    c_st = fg * c_st + ig * gg;
    const float hval = og * fast_tanh(c_st);
    if (qt == 0) {
      llc_store(hb + (size_t)(tt + 1) * SLAB_F + g * 2048 + sub * 512 + slot, hval);
      hout[(size_t)tt * (BATCH * HDIM) + (size_t)(g * 4 + sub) * HDIM + slot] = hval;
    }

    // ---- poll + stage h(tt+1) into the other buffer; data is the flag ----
    if (tt + 1 < TCHUNK) {
      const float* src = hb + (size_t)(tt + 1) * SLAB_F + g * 2048 + srcoff;
      f4 va, vb;
      int guard = 0;
      while (true) {
        asm volatile("global_load_dwordx4 %0, %2, off sc0 sc1\n\t"
                     "global_load_dwordx4 %1, %3, off sc0 sc1\n\t"
                     "s_waitcnt vmcnt(0)"
                     : "=&v"(va), "=&v"(vb) : "v"(src), "v"(src + 4) : "memory");
        const bool ok =
            __float_as_uint(va.x) != 0xFFFFFFFFu && __float_as_uint(va.y) != 0xFFFFFFFFu &&
            __float_as_uint(va.z) != 0xFFFFFFFFu && __float_as_uint(va.w) != 0xFFFFFFFFu &&
            __float_as_uint(vb.x) != 0xFFFFFFFFu && __float_as_uint(vb.y) != 0xFFFFFFFFu &&
            __float_as_uint(vb.z) != 0xFFFFFFFFu && __float_as_uint(vb.w) != 0xFFFFFFFFu;
        if (__all(ok) || ++guard > 100000) break;
        __builtin_amdgcn_s_sleep(1);
      }
      char* hsd = (char*)&h_s[0][0] + 8192 * ((tt + 1) & 1);
      *(float*)(hsd + dsb[0]) = va.x; *(float*)(hsd + dsb[1]) = va.y;
      *(float*)(hsd + dsb[2]) = va.z; *(float*)(hsd + dsb[3]) = va.w;
      *(float*)(hsd + dsb[4]) = vb.x; *(float*)(hsd + dsb[5]) = vb.y;
      *(float*)(hsd + dsb[6]) = vb.z; *(float*)(hsd + dsb[7]) = vb.w;
      BARRIER();                               // next buffer ready
    }
  }
  if (qt == 0) ccur[(size_t)(g * 4 + sub) * HDIM + slot] = c_st;
  ((volatile float*)pad)[tid] = c_st;          // keep LDS pad allocated
}

// ---------------------------------------------------------------------------
// head: logits = h2 @ W3^T + b3 ; softmax over 10. One wave per row.
// ---------------------------------------------------------------------------
__launch_bounds__(256, 2)
__global__ void head_kernel(const float* __restrict__ h2,
                            const float* __restrict__ W3,
                            const float* __restrict__ b3,
                            float* __restrict__ outp) {
  const int tid = threadIdx.x;
  const int lane = tid & 63;
  const int wv = tid >> 6;
  const int row = blockIdx.x * 4 + wv;
  const float* hrow = &h2[(size_t)row * HDIM];
  float hreg[8];
  *(float4*)&hreg[0] = *(const float4*)&hrow[lane * 8];
  *(float4*)&hreg[4] = *(const float4*)&hrow[lane * 8 + 4];
  float logit[ODIM];
#pragma unroll
  for (int o = 0; o < ODIM; ++o) {
    const float* wrow = &W3[o * HDIM + lane * 8];
    float w[8];
    *(float4*)&w[0] = *(const float4*)&wrow[0];
    *(float4*)&w[4] = *(const float4*)&wrow[4];
    float pp = 0.f;
#pragma unroll
    for (int j = 0; j < 8; ++j) pp += hreg[j] * w[j];
#pragma unroll
    for (int off = 32; off > 0; off >>= 1) pp += __shfl_xor(pp, off);
    logit[o] = pp + b3[o];
  }
  float mx = logit[0];
#pragma unroll
  for (int o = 1; o < ODIM; ++o) mx = fmaxf(mx, logit[o]);
  float ssum = 0.f;
#pragma unroll
  for (int o = 0; o < ODIM; ++o) { logit[o] = __expf(logit[o] - mx); ssum += logit[o]; }
  const float inv = 1.f / ssum;
  if (lane == 0) {
    float* dst = &outp[(size_t)row * ODIM];
#pragma unroll
    for (int o = 0; o < ODIM; ++o) dst[o] = logit[o] * inv;
  }
}

// ---------------------------------------------------------------------------
extern "C" void kernel_launch(void* const* d_in, const int* in_sizes, int n_in,
                              void* d_out, int out_size, void* d_ws, size_t ws_size,
                              hipStream_t stream) {
  const float* data  = (const float*)d_in[0];
  const float* W_ih1 = (const float*)d_in[1];
  const float* W_hh1 = (const float*)d_in[2];
  const float* b1    = (const float*)d_in[3];
  const float* W_ih2 = (const float*)d_in[4];
  const float* W_hh2 = (const float*)d_in[5];
  const float* b2    = (const float*)d_in[6];
  const float* W3    = (const float*)d_in[7];
  const float* b3    = (const float*)d_in[8];
  float* outp = (float*)d_out;

  char* ws = (char*)d_ws;
  size_t off = 0;
  float* xp    = (float*)(ws + off); off += (size_t)TCHUNK * GDIM * BATCH * 4;     // 32MB
  float* h1c   = (float*)(ws + off); off += (size_t)TCHUNK * BATCH * HDIM * 4;     // 8MB
  float* h2c   = (float*)(ws + off); off += (size_t)TCHUNK * BATCH * HDIM * 4;     // 8MB
  float* hb1   = (float*)(ws + off); off += (size_t)(TCHUNK + 1) * SLAB_B;         // 8.45MB
  float* hb2   = (float*)(ws + off); off += (size_t)(TCHUNK + 1) * SLAB_B;
  float* ccur1 = (float*)(ws + off); off += BATCH * HDIM * 4;
  float* ccur2 = (float*)(ws + off); off += BATCH * HDIM * 4;
  if (off > ws_size) return;   // ws too small: bail visibly

  // slab 0 = h(0) = zeros; slabs 1..TCHUNK = sentinel 0xFFFFFFFF
  hipMemsetAsync(hb1, 0x00, SLAB_B, stream);
  hipMemsetAsync((char*)hb1 + SLAB_B, 0xFF, (size_t)TCHUNK * SLAB_B, stream);
  hipMemsetAsync(hb2, 0x00, SLAB_B, stream);
  hipMemsetAsync((char*)hb2 + SLAB_B, 0xFF, (size_t)TCHUNK * SLAB_B, stream);

  const dim3 pgrid(GDIM / 128, (TCHUNK * BATCH) / 128);
  for (int c = 0; c < NCHUNK; ++c) {
    const float* xin = data + (size_t)c * TCHUNK * BATCH * IDIM;
    proj_kernel<IDIM><<<pgrid, 256, 0, stream>>>(xin, W_ih1, b1, xp);
    scan_kernel<<<NBLK, 256, 0, stream>>>(xp, W_hh1, h1c, hb1, ccur1, c == 0);
    if (c < NCHUNK - 1) {   // recycle slabs: h(end) -> slab0, re-sentinel
      hipMemcpyAsync(hb1, (char*)hb1 + (size_t)TCHUNK * SLAB_B, SLAB_B,
                     hipMemcpyDeviceToDevice, stream);
      hipMemsetAsync((char*)hb1 + SLAB_B, 0xFF, (size_t)TCHUNK * SLAB_B, stream);
    }
    proj_kernel<HDIM><<<pgrid, 256, 0, stream>>>(h1c, W_ih2, b2, xp);
    scan_kernel<<<NBLK, 256, 0, stream>>>(xp, W_hh2, h2c, hb2, ccur2, c == 0);
    if (c < NCHUNK - 1) {
      hipMemcpyAsync(hb2, (char*)hb2 + (size_t)TCHUNK * SLAB_B, SLAB_B,
                     hipMemcpyDeviceToDevice, stream);
      hipMemsetAsync((char*)hb2 + SLAB_B, 0xFF, (size_t)TCHUNK * SLAB_B, stream);
    }
    head_kernel<<<(TCHUNK * BATCH) / 4, 256, 0, stream>>>(
        h2c, W3, b3, outp + (size_t)c * TCHUNK * BATCH * ODIM);
  }
}

// Round 10
// 8744.105 us; speedup vs baseline: 1.5853x; 1.5853x over previous
//
#include <hip/hip_runtime.h>
#include <cstdint>
#include <cstddef>

#define TCHUNK 128
#define NCHUNK 8
#define BATCH 32
#define IDIM 128
#define HDIM 512
#define GDIM 2048
#define ODIM 10
#define NBLK 256
#define XPSTEP (GDIM * BATCH)
#define SLAB_F 16384            // floats per t-slab: 8 groups x 4 chains x 512
#define SLAB_B (SLAB_F * 4)

typedef float f4 __attribute__((ext_vector_type(4)));
typedef float f2 __attribute__((ext_vector_type(2)));

// LLC-visible store (sc0 sc1): one-way, fire-and-forget, placement-independent
__device__ __forceinline__ void llc_store(float* p, float v) {
  asm volatile("global_store_dword %0, %1, off sc0 sc1" :: "v"(p), "v"(v) : "memory");
}
// quad (4-lane) butterfly sum via DPP quad_perm — pure VALU
__device__ __forceinline__ float quad_sum(float x) {
  int t = __builtin_amdgcn_update_dpp(0, __float_as_int(x), 0xB1, 0xF, 0xF, true);
  x += __int_as_float(t);
  t = __builtin_amdgcn_update_dpp(0, __float_as_int(x), 0x4E, 0xF, 0xF, true);
  x += __int_as_float(t);
  return x;
}

#define BARRIER() do {                                                      \
    asm volatile("s_waitcnt lgkmcnt(0)" ::: "memory");                      \
    __builtin_amdgcn_sched_barrier(0);                                      \
    __builtin_amdgcn_s_barrier();                                           \
    __builtin_amdgcn_sched_barrier(0);                                      \
  } while (0)

// ---------------------------------------------------------------------------
// proj: P[tt][n][b] = sum_k X[tt*32+b][k] * W[n][k] + bias[n]
// ---------------------------------------------------------------------------
template<int K>
__launch_bounds__(256, 2)
__global__ void proj_kernel(const float* __restrict__ X,
                            const float* __restrict__ W,
                            const float* __restrict__ bias,
                            float* __restrict__ P) {
  __shared__ float Xs[8][132];
  __shared__ float Ws[8][132];
  const int tid = threadIdx.x;
  const int n0 = blockIdx.x * 128;
  const int m0 = blockIdx.y * 128;
  const int tx = tid & 15, ty = tid >> 4;
  const int lm = tid >> 1;
  const int kq = (tid & 1) * 4;
  f2 acc2[8][4];
#pragma unroll
  for (int i = 0; i < 8; ++i)
#pragma unroll
    for (int j = 0; j < 4; ++j) acc2[i][j] = (f2){0.f, 0.f};

  for (int k0 = 0; k0 < K; k0 += 8) {
    const float4 xv = *(const float4*)&X[(size_t)(m0 + lm) * K + k0 + kq];
    const float4 wv = *(const float4*)&W[(size_t)(n0 + lm) * K + k0 + kq];
    __syncthreads();
    Xs[kq + 0][lm] = xv.x; Xs[kq + 1][lm] = xv.y; Xs[kq + 2][lm] = xv.z; Xs[kq + 3][lm] = xv.w;
    Ws[kq + 0][lm] = wv.x; Ws[kq + 1][lm] = wv.y; Ws[kq + 2][lm] = wv.z; Ws[kq + 3][lm] = wv.w;
    __syncthreads();
#pragma unroll
    for (int kk = 0; kk < 8; ++kk) {
      float a[8];
      *(float4*)&a[0] = *(const float4*)&Xs[kk][ty * 8];
      *(float4*)&a[4] = *(const float4*)&Xs[kk][ty * 8 + 4];
      f2 b2[4];
#pragma unroll
      for (int jp = 0; jp < 4; ++jp) b2[jp] = *(const f2*)&Ws[kk][tx * 8 + 2 * jp];
#pragma unroll
      for (int i = 0; i < 8; ++i)
#pragma unroll
        for (int jp = 0; jp < 4; ++jp) acc2[i][jp] += b2[jp] * a[i];
    }
  }
  const int mb = m0 + ty * 8;
  const int t  = mb >> 5;
  const int b0 = mb & 31;
#pragma unroll
  for (int j = 0; j < 8; ++j) {
    const int n = n0 + tx * 8 + j;
    const float bj = bias[n];
    float* dst = &P[((size_t)t * GDIM + n) * BATCH + b0];
#pragma unroll
    for (int i = 0; i < 8; ++i)
      dst[i] = ((j & 1) ? acc2[i][j >> 1].y : acc2[i][j >> 1].x) + bj;
  }
}

// ---------------------------------------------------------------------------
// scan: sentinel-exchange LSTM recurrence (R6 structure, 3 barriers/step).
// 256 blocks, 1/CU (81KB LDS). Group g=bid&7 owns batches 4g..4g+3;
// rank=bid>>3 owns h-slots rank*16..+15 (64 W_hh rows in VGPRs,
// column-permuted by e^cx so hot-loop LDS reads are LINEAR imm-offset).
// h LDS: slice stride 132 floats (32 k x 4 chains + 4 pad). Layout invariant:
//   float idx 132*sg + 4*kk + cl  holds  h[chain cl][k = 32*sg + (kk ^ (sg&7))]
// Read (b128): byte 528*sg + 16*kk -> banks (16w+4*s4+4*kk)%32, 4 disjoint
// 4-bank spans per wave instruction + 16-lane broadcast -> conflict-free.
// Exchange: write-once slabs hb[t][g][chain][512], sentinel 0xFFFFFFFF
// (negative NaN; h=og*tanh(c) of finite inputs can never produce it).
// ---------------------------------------------------------------------------
__launch_bounds__(256, 1)
__global__ void scan_kernel(const float* __restrict__ xp,    // [TCHUNK][GDIM][BATCH]
                            const float* __restrict__ Whh,   // [GDIM][HDIM]
                            float* __restrict__ hout,        // [TCHUNK][BATCH][HDIM]
                            float* __restrict__ hb,          // [TCHUNK+1][8][4][512]
                            float* __restrict__ ccur,        // [BATCH][HDIM]
                            int first) {
  __shared__ float h_s[2112];       // 16 slices x 132 floats (4-float pad/slice)
  __shared__ float red[1024];       // [w][row l][chain] cross-wave partials
  __shared__ float gate_s[256];
  __shared__ float pad[17408];      // 68KB -> ~81.3KB total -> 1 block/CU

  const int tid = threadIdx.x, bid = blockIdx.x;
  const int g = bid & 7, rank = bid >> 3, slot16 = rank * 16;
  const int w = tid >> 6, l = tid & 63;
  const int s4 = l & 3, rq = l >> 2;
  const int sg = 4 * w + s4;        // this thread's 32-k slice (16 slices)
  const int cx = sg & 7;            // W column-permute key (matches LDS octet swz)
  const int kb = 32 * sg;

  // ---- W_hh slice into VGPRs, column-permuted ----
  float wreg[4][32];
#pragma unroll
  for (int r = 0; r < 4; ++r) {
    const int rl = 4 * rq + r;
    const float* wp = Whh + (size_t)((rl >> 4) * HDIM + slot16 + (rl & 15)) * HDIM + kb;
#pragma unroll
    for (int e = 0; e < 32; ++e) wreg[r][e] = wp[e ^ cx];
  }

  // staging role (t-invariant): chain cl, 8 words at global K = 128w + 8m + i
  // -> slice sgS = 4w + (m>>2), within-slice kk = 8*(m&3) + i, swizzled i^sig
  const int cl = l >> 4, m = l & 15;
  const int sgS = 4 * w + (m >> 2);
  const int sig = sgS & 7;
  int dsaddr[8];
#pragma unroll
  for (int i = 0; i < 8; ++i)
    dsaddr[i] = 132 * sgS + 4 * (8 * (m & 3) + (i ^ sig)) + cl;   // FIXED scale
  const int srcoff = cl * 512 + 128 * w + 8 * m;

  // gate-cell role (1 pre-activation per thread): q=tid>>6, j, b
  const int qg = tid >> 6, jg = (tid >> 2) & 15, bg = tid & 3;
  const float* xq = xp + (size_t)(qg * HDIM + slot16 + jg) * BATCH + g * 4 + bg;

  // update role (wave 0): cell (slot16 + jj, chain bb)
  const int jj = l >> 2, bb = l & 3;

  float c_st = 0.f;
  if (!first && w == 0) c_st = ccur[(size_t)(g * 4 + bb) * HDIM + slot16 + jj];

  const float* hptr = &h_s[132 * sg];   // padded slice base (conflict-free reads)

#pragma unroll 1
  for (int tt = 0; tt < TCHUNK; ++tt) {
    // ---- poll + stage h(tt): data is the flag ----
    const float* src = hb + (size_t)tt * SLAB_F + g * 2048 + srcoff;
    f4 va, vb;
    int guard = 0;
    while (true) {
      asm volatile("global_load_dwordx4 %0, %2, off sc0 sc1\n\t"
                   "global_load_dwordx4 %1, %3, off sc0 sc1\n\t"
                   "s_waitcnt vmcnt(0)"
                   : "=&v"(va), "=&v"(vb) : "v"(src), "v"(src + 4) : "memory");
      const bool ok =
          __float_as_uint(va.x) != 0xFFFFFFFFu && __float_as_uint(va.y) != 0xFFFFFFFFu &&
          __float_as_uint(va.z) != 0xFFFFFFFFu && __float_as_uint(va.w) != 0xFFFFFFFFu &&
          __float_as_uint(vb.x) != 0xFFFFFFFFu && __float_as_uint(vb.y) != 0xFFFFFFFFu &&
          __float_as_uint(vb.z) != 0xFFFFFFFFu && __float_as_uint(vb.w) != 0xFFFFFFFFu;
      if (__all(ok) || ++guard > 100000) break;
      __builtin_amdgcn_s_sleep(1);
    }
    h_s[dsaddr[0]] = va.x; h_s[dsaddr[1]] = va.y;
    h_s[dsaddr[2]] = va.z; h_s[dsaddr[3]] = va.w;
    h_s[dsaddr[4]] = vb.x; h_s[dsaddr[5]] = vb.y;
    h_s[dsaddr[6]] = vb.z; h_s[dsaddr[7]] = vb.w;
    const float xpv = xq[(size_t)tt * XPSTEP];
    BARRIER();                                  // h_s(tt) ready

    // ---- partials: 4 rows x 4 chains, linear imm-offset ds_read_b128 ----
    f2 a01[4], a23[4];
#pragma unroll
    for (int r = 0; r < 4; ++r) { a01[r] = (f2){0.f, 0.f}; a23[r] = (f2){0.f, 0.f}; }
#pragma unroll
    for (int kk = 0; kk < 32; ++kk) {
      const f4 hv = *(const f4*)&hptr[4 * kk];
      const f2 h01 = {hv.x, hv.y}, h23 = {hv.z, hv.w};
#pragma unroll
      for (int r = 0; r < 4; ++r) {
        a01[r] += h01 * wreg[r][kk];
        a23[r] += h23 * wreg[r][kk];
      }
    }
#pragma unroll
    for (int r = 0; r < 4; ++r) {
      a01[r].x = quad_sum(a01[r].x); a01[r].y = quad_sum(a01[r].y);
      a23[r].x = quad_sum(a23[r].x); a23[r].y = quad_sum(a23[r].y);
    }
    f2 r01, r23;
    { const f2 v0 = (s4 & 1) ? a01[1] : a01[0];
      const f2 v1 = (s4 & 1) ? a01[3] : a01[2];
      r01 = (s4 & 2) ? v1 : v0;
      const f2 u0 = (s4 & 1) ? a23[1] : a23[0];
      const f2 u1 = (s4 & 1) ? a23[3] : a23[2];
      r23 = (s4 & 2) ? u1 : u0; }
    *(f4*)&red[(w << 8) + 4 * l] = (f4){r01.x, r01.y, r23.x, r23.y};
    BARRIER();                                  // red(tt) ready

    // ---- cross-wave reduce + xp + activation (1 cell/thread) ----
    const float pre = red[tid] + red[256 + tid] + red[512 + tid] + red[768 + tid] + xpv;
    gate_s[tid] = (qg == 2) ? tanhf(pre) : 1.f / (1.f + __expf(-pre));
    BARRIER();                                  // gates ready

    // ---- c/h update + one-way exchange store (wave 0) ----
    if (w == 0) {
      const float ig = gate_s[jj * 4 + bb];
      const float fg = gate_s[64 + jj * 4 + bb];
      const float gg = gate_s[128 + jj * 4 + bb];
      const float og = gate_s[192 + jj * 4 + bb];
      c_st = fg * c_st + ig * gg;
      const float hval = og * tanhf(c_st);
      llc_store(hb + (size_t)(tt + 1) * SLAB_F + g * 2048 + bb * 512 + slot16 + jj, hval);
      hout[(size_t)tt * (BATCH * HDIM) + (size_t)(g * 4 + bb) * HDIM + slot16 + jj] = hval;
    }
    // no 4th barrier needed: tt+1 staging writes h_s (reads done before red
    // barrier); gate_s/red next writes are behind tt+1's barriers.
  }
  if (w == 0) ccur[(size_t)(g * 4 + bb) * HDIM + slot16 + jj] = c_st;
  ((volatile float*)pad)[tid] = c_st;           // keep LDS pad allocated
}

// ---------------------------------------------------------------------------
// head: logits = h2 @ W3^T + b3 ; softmax over 10. One wave per row.
// ---------------------------------------------------------------------------
__launch_bounds__(256, 2)
__global__ void head_kernel(const float* __restrict__ h2,
                            const float* __restrict__ W3,
                            const float* __restrict__ b3,
                            float* __restrict__ outp) {
  const int tid = threadIdx.x;
  const int lane = tid & 63;
  const int wv = tid >> 6;
  const int row = blockIdx.x * 4 + wv;
  const float* hrow = &h2[(size_t)row * HDIM];
  float hreg[8];
  *(float4*)&hreg[0] = *(const float4*)&hrow[lane * 8];
  *(float4*)&hreg[4] = *(const float4*)&hrow[lane * 8 + 4];
  float logit[ODIM];
#pragma unroll
  for (int o = 0; o < ODIM; ++o) {
    const float* wrow = &W3[o * HDIM + lane * 8];
    float w[8];
    *(float4*)&w[0] = *(const float4*)&wrow[0];
    *(float4*)&w[4] = *(const float4*)&wrow[4];
    float pp = 0.f;
#pragma unroll
    for (int j = 0; j < 8; ++j) pp += hreg[j] * w[j];
#pragma unroll
    for (int off = 32; off > 0; off >>= 1) pp += __shfl_xor(pp, off);
    logit[o] = pp + b3[o];
  }
  float mx = logit[0];
#pragma unroll
  for (int o = 1; o < ODIM; ++o) mx = fmaxf(mx, logit[o]);
  float ssum = 0.f;
#pragma unroll
  for (int o = 0; o < ODIM; ++o) { logit[o] = __expf(logit[o] - mx); ssum += logit[o]; }
  const float inv = 1.f / ssum;
  if (lane == 0) {
    float* dst = &outp[(size_t)row * ODIM];
#pragma unroll
    for (int o = 0; o < ODIM; ++o) dst[o] = logit[o] * inv;
  }
}

// ---------------------------------------------------------------------------
extern "C" void kernel_launch(void* const* d_in, const int* in_sizes, int n_in,
                              void* d_out, int out_size, void* d_ws, size_t ws_size,
                              hipStream_t stream) {
  const float* data  = (const float*)d_in[0];
  const float* W_ih1 = (const float*)d_in[1];
  const float* W_hh1 = (const float*)d_in[2];
  const float* b1    = (const float*)d_in[3];
  const float* W_ih2 = (const float*)d_in[4];
  const float* W_hh2 = (const float*)d_in[5];
  const float* b2    = (const float*)d_in[6];
  const float* W3    = (const float*)d_in[7];
  const float* b3    = (const float*)d_in[8];
  float* outp = (float*)d_out;

  char* ws = (char*)d_ws;
  size_t off = 0;
  float* xp    = (float*)(ws + off); off += (size_t)TCHUNK * GDIM * BATCH * 4;     // 32MB
  float* h1c   = (float*)(ws + off); off += (size_t)TCHUNK * BATCH * HDIM * 4;     // 8MB
  float* h2c   = (float*)(ws + off); off += (size_t)TCHUNK * BATCH * HDIM * 4;     // 8MB
  float* hb1   = (float*)(ws + off); off += (size_t)(TCHUNK + 1) * SLAB_B;         // 8.45MB
  float* hb2   = (float*)(ws + off); off += (size_t)(TCHUNK + 1) * SLAB_B;
  float* ccur1 = (float*)(ws + off); off += BATCH * HDIM * 4;
  float* ccur2 = (float*)(ws + off); off += BATCH * HDIM * 4;
  if (off > ws_size) return;   // ws too small: bail visibly

  // slab 0 = h(0) = zeros; slabs 1..TCHUNK = sentinel 0xFFFFFFFF
  hipMemsetAsync(hb1, 0x00, SLAB_B, stream);
  hipMemsetAsync((char*)hb1 + SLAB_B, 0xFF, (size_t)TCHUNK * SLAB_B, stream);
  hipMemsetAsync(hb2, 0x00, SLAB_B, stream);
  hipMemsetAsync((char*)hb2 + SLAB_B, 0xFF, (size_t)TCHUNK * SLAB_B, stream);

  const dim3 pgrid(GDIM / 128, (TCHUNK * BATCH) / 128);
  for (int c = 0; c < NCHUNK; ++c) {
    const float* xin = data + (size_t)c * TCHUNK * BATCH * IDIM;
    proj_kernel<IDIM><<<pgrid, 256, 0, stream>>>(xin, W_ih1, b1, xp);
    scan_kernel<<<NBLK, 256, 0, stream>>>(xp, W_hh1, h1c, hb1, ccur1, c == 0);
    if (c < NCHUNK - 1) {   // recycle slabs: h(end) -> slab0, re-sentinel
      hipMemcpyAsync(hb1, (char*)hb1 + (size_t)TCHUNK * SLAB_B, SLAB_B,
                     hipMemcpyDeviceToDevice, stream);
      hipMemsetAsync((char*)hb1 + SLAB_B, 0xFF, (size_t)TCHUNK * SLAB_B, stream);
    }
    proj_kernel<HDIM><<<pgrid, 256, 0, stream>>>(h1c, W_ih2, b2, xp);
    scan_kernel<<<NBLK, 256, 0, stream>>>(xp, W_hh2, h2c, hb2, ccur2, c == 0);
    if (c < NCHUNK - 1) {
      hipMemcpyAsync(hb2, (char*)hb2 + (size_t)TCHUNK * SLAB_B, SLAB_B,
                     hipMemcpyDeviceToDevice, stream);
      hipMemsetAsync((char*)hb2 + SLAB_B, 0xFF, (size_t)TCHUNK * SLAB_B, stream);
    }
    head_kernel<<<(TCHUNK * BATCH) / 4, 256, 0, stream>>>(
        h2c, W3, b3, outp + (size_t)c * TCHUNK * BATCH * ODIM);
  }
}